// Round 2
// baseline (13049.359 us; speedup 1.0000x reference)
//
#include <hip/hip_runtime.h>
#include <hip/hip_fp16.h>
#include <math.h>

// Problem constants
#define BATCH 256
#define TSEQ  512
#define FEAT  64
#define NU1   256
#define NU2   128

// half2-element offsets of packed fp16 weight planes inside d_ws.
// Quad-pair planes: plane[chunk][col][4], chunk = pair/4, half2 = (row0, row0+1).
// GRU1: 3 planes of [40 chunks][256 cols][4]  (160 pairs = 64 x-rows then 256 h-rows)
// GRU2: 3 planes of [48 chunks][128 cols][4], chunk order REMAPPED so each kh-half
//       is contiguous: [kh=0: 16 h1-chunks, 8 h2-chunks][kh=1: 16 h1-chunks, 8 h2-chunks]
#define G1Z_OFF 0
#define G1R_OFF 40960
#define G1H_OFF 81920
#define G2Z_OFF 122880
#define G2R_OFF 147456
#define G2H_OFF 172032
#define TOTAL_H2 196608   // 786,432 bytes of d_ws

// uint4-unit plane offsets (half2 offset / 4)
#define G1Z_U4 0
#define G1R_U4 10240
#define G1H_U4 20480
#define G2Z_U4 30720
#define G2R_U4 36864
#define G2H_U4 43008

typedef _Float16 h2f __attribute__((ext_vector_type(2)));

__device__ __forceinline__ float sigmoid_f(float v) {
    return 1.0f / (1.0f + __expf(-v));
}
__device__ __forceinline__ float tanh_f(float v) {
    float c = fminf(fmaxf(v, -15.0f), 15.0f);
    float e = __expf(2.0f * c);
    return (e - 1.0f) / (e + 1.0f);
}

__device__ __forceinline__ h2f bch2(unsigned int u) {
    return __builtin_bit_cast(h2f, u);
}
__device__ __forceinline__ unsigned int pack2(float a, float b) {
    h2f v;
    v.x = (_Float16)a;
    v.y = (_Float16)b;
    return __builtin_bit_cast(unsigned int, v);
}

// acc += dot of 4 half2 pairs (8 fp16 weights x 8 fp16 activations), fp32 accum
__device__ __forceinline__ void dot4(float& acc, uint4 w, uint4 a) {
    acc = __builtin_amdgcn_fdot2(bch2(w.x), bch2(a.x), acc, false);
    acc = __builtin_amdgcn_fdot2(bch2(w.y), bch2(a.y), acc, false);
    acc = __builtin_amdgcn_fdot2(bch2(w.z), bch2(a.z), acc, false);
    acc = __builtin_amdgcn_fdot2(bch2(w.w), bch2(a.w), acc, false);
}

// ---------------- weight packing (fp32 -> fp16 quad-pair planes) ----------------
__global__ void pack_weights(const float* __restrict__ k1, const float* __restrict__ r1,
                             const float* __restrict__ k2, const float* __restrict__ r2,
                             __half2* __restrict__ ws)
{
    int idx = blockIdx.x * 256 + threadIdx.x;
    if (idx >= TOTAL_H2) return;
    float a, b;
    if (idx < G2Z_OFF) {
        // GRU1 planes: 3 x [40 chunks][256 cols][4]
        int plane = idx / 40960;       // 0=z 1=r 2=h
        int rem   = idx % 40960;       // = chunk*1024 + col*4 + q
        int c     = rem >> 10;
        int col   = (rem >> 2) & 255;
        int q     = rem & 3;
        int pair  = c * 4 + q;
        int g     = plane * 256 + col; // gate-column in [0,768)
        int row0  = pair * 2;
        if (row0 < 64) { a = k1[row0 * 768 + g];        b = k1[(row0 + 1) * 768 + g]; }
        else           { a = r1[(row0 - 64) * 768 + g]; b = r1[(row0 - 63) * 768 + g]; }
    } else {
        // GRU2 planes: 3 x [48 chunks][128 cols][4], kh-contiguous chunk remap:
        // new chunk nc = k*24 + w; orig chunk oc = (w<16) ? k*16+w : 32 + k*8 + (w-16)
        int idx2  = idx - G2Z_OFF;
        int plane = idx2 / 24576;
        int rem   = idx2 % 24576;      // = nc*512 + col*4 + q
        int nc    = rem >> 9;
        int col   = (rem >> 2) & 127;
        int q     = rem & 3;
        int k     = nc / 24;
        int w     = nc - k * 24;
        int oc    = (w < 16) ? (k * 16 + w) : (32 + k * 8 + (w - 16));
        int pair  = oc * 4 + q;
        int g     = plane * 128 + col; // gate-column in [0,384)
        int row0  = pair * 2;
        if (row0 < 256) { a = k2[row0 * 384 + g];         b = k2[(row0 + 1) * 384 + g]; }
        else            { a = r2[(row0 - 256) * 384 + g]; b = r2[(row0 - 255) * 384 + g]; }
    }
    __half2 h;
    h.x = __float2half_rn(a);
    h.y = __float2half_rn(b);
    ws[idx] = h;
}

// K-segment over NCH chunks (4 pairs each): 3 gate streams, double-buffered
// dwordx4 register pipeline (BCH=2 -> 48 buffer VGPRs, no spill),
// v_dot2_f32_f16 math. act = half2-pair LDS array (wave-uniform -> broadcast).
template <int COLS, int NCH>
__device__ __forceinline__ void seg2(const uint4* __restrict__ pz,
                                     const uint4* __restrict__ pr,
                                     const uint4* __restrict__ ph,
                                     const unsigned int* __restrict__ act,
                                     float& az, float& ar, float& a3)
{
    constexpr int BCH = 2;              // chunks per pipeline block
    constexpr int NB  = NCH / BCH;
    uint4 bz[2][BCH], br[2][BCH], bh[2][BCH];
    #pragma unroll
    for (int q = 0; q < BCH; ++q) {
        bz[0][q] = pz[q * COLS]; br[0][q] = pr[q * COLS]; bh[0][q] = ph[q * COLS];
    }
    #pragma unroll
    for (int b = 0; b < NB; ++b) {
        const int cur = b & 1, nxt = cur ^ 1;
        if (b + 1 < NB) {
            const uint4* z2 = pz + (b + 1) * BCH * COLS;
            const uint4* r2 = pr + (b + 1) * BCH * COLS;
            const uint4* h2 = ph + (b + 1) * BCH * COLS;
            #pragma unroll
            for (int q = 0; q < BCH; ++q) {
                bz[nxt][q] = z2[q * COLS]; br[nxt][q] = r2[q * COLS]; bh[nxt][q] = h2[q * COLS];
            }
        }
        #pragma unroll
        for (int q = 0; q < BCH; ++q) {
            const uint4 a = *(const uint4*)(act + (b * BCH + q) * 4);
            dot4(az, bz[cur][q], a);
            dot4(ar, br[cur][q], a);
            dot4(a3, bh[cur][q], a);
        }
    }
}

// 256 WGs x 256 threads, one batch row per WG. One barrier per timestep.
__global__ __launch_bounds__(256, 1)
void gru_fused(const float* __restrict__ x,
               const float* __restrict__ b1, const float* __restrict__ b2,
               const float* __restrict__ w3, const float* __restrict__ b3,
               const float* __restrict__ w4, const float* __restrict__ b4,
               const float* __restrict__ w5, const float* __restrict__ b5,
               const unsigned int* __restrict__ wp,
               float* __restrict__ out)
{
    // fp16 activation pair buffers (uint = one half2), double-buffered.
    // act1: pairs [0..31] = x(t) (64 feats), pairs [32..159] = h1 (256 units)
    // act2: pairs [0..63] = h2 (128 units)
    __shared__ __align__(16) unsigned int act1[2][160];
    __shared__ __align__(16) unsigned int act2[2][64];
    __shared__ float h2fin[NU2];
    __shared__ float d3[64];
    __shared__ float d4[32];

    const int tid = threadIdx.x;
    const int row = blockIdx.x;
    const int j   = tid;            // GRU1 column
    const int c2  = tid >> 1;       // GRU2 column
    const int kh  = tid & 1;        // GRU2 K-half (uniform code path, ptr offsets only)

    for (int i = tid; i < 2 * 160; i += 256) (&act1[0][0])[i] = 0u;
    for (int i = tid; i < 2 * 64;  i += 256) (&act2[0][0])[i] = 0u;

    // GRU1 biases (z,r folded; h kept split for reset_after)
    const float bz1  = b1[j] + b1[768 + j];
    const float br1  = b1[256 + j] + b1[1024 + j];
    const float bxh1 = b1[512 + j];
    const float brh1 = b1[1280 + j];
    // GRU2 biases, masked to even lane (kh==0) so the shfl-sum counts them once
    const float bm   = (kh == 0) ? 1.0f : 0.0f;
    const float bz2  = (b2[c2] + b2[384 + c2]) * bm;
    const float br2  = (b2[128 + c2] + b2[512 + c2]) * bm;
    const float bxh2 = b2[256 + c2] * bm;
    const float brh2 = b2[640 + c2] * bm;

    const uint4* wp4 = (const uint4*)wp;
    const uint4* g1z = wp4 + G1Z_U4 + j;
    const uint4* g1r = wp4 + G1R_U4 + j;
    const uint4* g1h = wp4 + G1H_U4 + j;
    // GRU2: one base per gate (kh-half is contiguous: 16 h1-chunks then 8 h2-chunks)
    const uint4* g2z = wp4 + G2Z_U4 + kh * (24 * 128) + c2;
    const uint4* g2r = wp4 + G2R_U4 + kh * (24 * 128) + c2;
    const uint4* g2h = wp4 + G2H_U4 + kh * (24 * 128) + c2;

    __syncthreads();   // zeros visible before x(0) pack overwrites x-part

    if (tid < FEAT) {
        float x0 = x[(size_t)row * TSEQ * FEAT + tid];
        float xb = __shfl_xor(x0, 1);
        if ((tid & 1) == 0) act1[0][tid >> 1] = pack2(x0, xb);
    }
    __syncthreads();

    float hp1 = 0.0f;   // h1 previous state, column j (register-resident)
    float hp2 = 0.0f;   // h2 previous state, column c2 (valid on even lanes)

    for (int t = 0; t < TSEQ; ++t) {
        const int cur = t & 1, nb = cur ^ 1;

        // prefetch next x into registers (packed to LDS before the barrier)
        float xpre = 0.0f;
        if (t + 1 < TSEQ && tid < FEAT)
            xpre = x[(size_t)row * TSEQ * FEAT + (t + 1) * FEAT + tid];

        // ---------------- GRU1: reads act1[cur]; writes act1[nb] ----------------
        float az = bz1, ar = br1, axh = bxh1, arh = brh1;
        seg2<256, 8 >(g1z, g1r, g1h, &act1[cur][0], az, ar, axh);
        seg2<256, 32>(g1z + 8 * 256, g1r + 8 * 256, g1h + 8 * 256,
                      &act1[cur][32], az, ar, arh);
        {
            const float z  = sigmoid_f(az);
            const float rg = sigmoid_f(ar);
            const float hh = tanh_f(axh + rg * arh);
            const float hn = z * hp1 + (1.0f - z) * hh;
            hp1 = hn;
            const float hnb = __shfl_xor(hn, 1);
            if ((tid & 1) == 0) act1[nb][32 + (tid >> 1)] = pack2(hn, hnb);
        }
        if (t + 1 < TSEQ && tid < FEAT) {
            float xb = __shfl_xor(xpre, 1);
            if ((tid & 1) == 0) act1[nb][tid >> 1] = pack2(xpre, xb);
        }
        __syncthreads();   // THE one barrier: act1[nb] (h1(t) + x(t+1)) visible

        // ---------------- GRU2: reads act1[nb] h-part, act2[cur]; writes act2[nb] ----------------
        float az2 = bz2, ar2 = br2, axh2 = bxh2, arh2 = brh2;
        seg2<128, 16>(g2z, g2r, g2h, &act1[nb][32 + kh * 64], az2, ar2, axh2);
        seg2<128, 8 >(g2z + 16 * 128, g2r + 16 * 128, g2h + 16 * 128,
                      &act2[cur][kh * 32], az2, ar2, arh2);
        // intra-wave pair reduction (lanes 2c / 2c+1)
        az2  += __shfl_xor(az2, 1);
        ar2  += __shfl_xor(ar2, 1);
        axh2 += __shfl_xor(axh2, 1);
        arh2 += __shfl_xor(arh2, 1);
        {
            const float z2v = sigmoid_f(az2);
            const float rg2 = sigmoid_f(ar2);
            const float hh2 = tanh_f(axh2 + rg2 * arh2);
            const float hn2 = z2v * hp2 + (1.0f - z2v) * hh2;  // hp2 valid on even lanes
            hp2 = hn2;
            const float hnb2 = __shfl_xor(hn2, 2);             // pair (c2=2m, 2m+1) on lanes 4m,4m+2
            if ((tid & 3) == 0) act2[nb][tid >> 2] = pack2(hn2, hnb2);
        }
        // no second barrier: next step's barrier covers act2[nb] visibility;
        // all WAR hazards are buffer-separated (same discipline as proven R2 kernel)
    }

    if ((tid & 1) == 0) h2fin[c2] = hp2;   // final h2 state, fp32
    __syncthreads();

    // ---------------- dense head: h2 -> 64 -> 32 -> 24 ----------------
    if (tid < 64) {
        float a = b3[tid];
        #pragma unroll 4
        for (int u = 0; u < NU2; ++u) a += h2fin[u] * w3[u * 64 + tid];
        d3[tid] = a;
    }
    __syncthreads();
    if (tid < 32) {
        float a = b4[tid];
        #pragma unroll 4
        for (int u = 0; u < 64; ++u) a += d3[u] * w4[u * 32 + tid];
        d4[tid] = a;
    }
    __syncthreads();
    if (tid < 24) {
        float a = b5[tid];
        #pragma unroll 4
        for (int u = 0; u < 32; ++u) a += d4[u] * w5[u * 24 + tid];
        out[(size_t)row * 24 + tid] = a;
    }
}

extern "C" void kernel_launch(void* const* d_in, const int* in_sizes, int n_in,
                              void* d_out, int out_size, void* d_ws, size_t ws_size,
                              hipStream_t stream) {
    (void)in_sizes; (void)n_in; (void)ws_size; (void)out_size;
    const float* x  = (const float*)d_in[0];
    const float* k1 = (const float*)d_in[1];
    const float* r1 = (const float*)d_in[2];
    const float* b1 = (const float*)d_in[3];
    const float* k2 = (const float*)d_in[4];
    const float* r2 = (const float*)d_in[5];
    const float* b2 = (const float*)d_in[6];
    const float* w3 = (const float*)d_in[7];
    const float* b3 = (const float*)d_in[8];
    const float* w4 = (const float*)d_in[9];
    const float* b4 = (const float*)d_in[10];
    const float* w5 = (const float*)d_in[11];
    const float* b5 = (const float*)d_in[12];
    float* out = (float*)d_out;

    hipLaunchKernelGGL(pack_weights, dim3((TOTAL_H2 + 255) / 256), dim3(256), 0, stream,
                       k1, r1, k2, r2, (__half2*)d_ws);
    hipLaunchKernelGGL(gru_fused, dim3(BATCH), dim3(256), 0, stream,
                       x, b1, b2, w3, b3, w4, b4, w5, b5,
                       (const unsigned int*)d_ws, out);
}

// Round 3
// 5191.028 us; speedup vs baseline: 2.5138x; 2.5138x over previous
//
#include <hip/hip_runtime.h>
#include <hip/hip_fp16.h>
#include <math.h>

// Problem constants
#define BATCH 256
#define TSEQ  512
#define FEAT  64
#define NU1   256
#define NU2   128

// half2-element offsets of packed fp16 weight planes inside d_ws.
// Quad-pair planes, K-split-contiguous chunk order (one chunk = 4 half2 row-pairs):
// GRU1 plane (per gate): [2 kh][20 chunks][256 cols][4]
//   chunks 0..3  = x rows (kh half: feats kh*32..kh*32+31)
//   chunks 4..19 = h1 rows (kh half: units kh*128..kh*128+127)
// GRU2 plane (per gate): [4 kq][12 chunks][128 cols][4]
//   chunks 0..7  = h1 rows (kq quarter: units kq*64..kq*64+63)
//   chunks 8..11 = h2 rows (kq quarter: units kq*32..kq*32+31)
#define G1Z_OFF 0
#define G1R_OFF 40960
#define G1H_OFF 81920
#define G2Z_OFF 122880
#define G2R_OFF 147456
#define G2H_OFF 172032
#define TOTAL_H2 196608   // 786,432 bytes of d_ws

// uint4-unit plane offsets (half2 offset / 4)
#define G1Z_U4 0
#define G1R_U4 10240
#define G1H_U4 20480
#define G2Z_U4 30720
#define G2R_U4 36864
#define G2H_U4 43008

typedef _Float16 h2f __attribute__((ext_vector_type(2)));

__device__ __forceinline__ float sigmoid_f(float v) {
    return 1.0f / (1.0f + __expf(-v));
}
__device__ __forceinline__ float tanh_f(float v) {
    float c = fminf(fmaxf(v, -15.0f), 15.0f);
    float e = __expf(2.0f * c);
    return (e - 1.0f) / (e + 1.0f);
}

__device__ __forceinline__ h2f bch2(unsigned int u) {
    return __builtin_bit_cast(h2f, u);
}
__device__ __forceinline__ unsigned int pack2(float a, float b) {
    h2f v;
    v.x = (_Float16)a;
    v.y = (_Float16)b;
    return __builtin_bit_cast(unsigned int, v);
}

// acc += dot of 4 half2 pairs (8 fp16 weights x 8 fp16 activations), fp32 accum
__device__ __forceinline__ void dot4(float& acc, uint4 w, uint4 a) {
    acc = __builtin_amdgcn_fdot2(bch2(w.x), bch2(a.x), acc, false);
    acc = __builtin_amdgcn_fdot2(bch2(w.y), bch2(a.y), acc, false);
    acc = __builtin_amdgcn_fdot2(bch2(w.z), bch2(a.z), acc, false);
    acc = __builtin_amdgcn_fdot2(bch2(w.w), bch2(a.w), acc, false);
}

// ---------------- weight packing (fp32 -> fp16 quad-pair planes) ----------------
__global__ void pack_weights(const float* __restrict__ k1, const float* __restrict__ r1,
                             const float* __restrict__ k2, const float* __restrict__ r2,
                             __half2* __restrict__ ws)
{
    int idx = blockIdx.x * 256 + threadIdx.x;
    if (idx >= TOTAL_H2) return;
    float a, b;
    if (idx < G2Z_OFF) {
        // GRU1 planes: 3 x [2 kh][20 chunks][256 cols][4]
        int plane = idx / 40960;       // 0=z 1=r 2=h
        int rem   = idx % 40960;       // = cc*1024 + col*4 + q
        int cc    = rem >> 10;         // 0..39
        int col   = (rem >> 2) & 255;
        int q     = rem & 3;
        int kh    = cc / 20;
        int c     = cc - kh * 20;
        int g     = plane * 256 + col; // gate-column in [0,768)
        int pair  = (c < 4) ? ((kh * 4 + c) * 4 + q)
                            : (32 + (kh * 16 + (c - 4)) * 4 + q);
        int row0  = pair * 2;
        if (row0 < 64) { a = k1[row0 * 768 + g];        b = k1[(row0 + 1) * 768 + g]; }
        else           { a = r1[(row0 - 64) * 768 + g]; b = r1[(row0 - 63) * 768 + g]; }
    } else {
        // GRU2 planes: 3 x [4 kq][12 chunks][128 cols][4]
        int idx2  = idx - G2Z_OFF;
        int plane = idx2 / 24576;
        int rem   = idx2 % 24576;      // = cc*512 + col*4 + q
        int cc    = rem >> 9;          // 0..47
        int col   = (rem >> 2) & 127;
        int q     = rem & 3;
        int kq    = cc / 12;
        int c     = cc - kq * 12;
        int g     = plane * 128 + col; // gate-column in [0,384)
        int pair  = (c < 8) ? ((kq * 8 + c) * 4 + q)
                            : (128 + (kq * 4 + (c - 8)) * 4 + q);
        int row0  = pair * 2;
        if (row0 < 256) { a = k2[row0 * 384 + g];         b = k2[(row0 + 1) * 384 + g]; }
        else            { a = r2[(row0 - 256) * 384 + g]; b = r2[(row0 - 255) * 384 + g]; }
    }
    __half2 h;
    h.x = __float2half_rn(a);
    h.y = __float2half_rn(b);
    ws[idx] = h;
}

// K-segment over NCH chunks: 3 gate streams, NAMED A/B double buffer (2 chunks
// each), runtime #pragma unroll 1 loop so the scheduler cannot hoist the whole
// stream and spill (R1/R2 lesson: full unroll -> 256 VGPR + 18.9 GB scratch).
template <int COLS, int NCH>
__device__ __forceinline__ void seg3(const uint4* __restrict__ pz,
                                     const uint4* __restrict__ pr,
                                     const uint4* __restrict__ ph,
                                     const unsigned int* __restrict__ act,
                                     float& az, float& ar, float& a3)
{
    static_assert(NCH % 4 == 0, "NCH must be a multiple of 4");
    // buffer A holds chunks c,c+1 ; buffer B holds chunks c+2,c+3
    uint4 a_z0 = pz[0], a_z1 = pz[COLS];
    uint4 a_r0 = pr[0], a_r1 = pr[COLS];
    uint4 a_h0 = ph[0], a_h1 = ph[COLS];
    #pragma unroll 1
    for (int c = 0; c < NCH; c += 4) {
        const uint4* qz = pz + 2 * COLS;
        const uint4* qr = pr + 2 * COLS;
        const uint4* qh = ph + 2 * COLS;
        uint4 b_z0 = qz[0], b_z1 = qz[COLS];
        uint4 b_r0 = qr[0], b_r1 = qr[COLS];
        uint4 b_h0 = qh[0], b_h1 = qh[COLS];
        const uint4 v0 = *(const uint4*)(act);
        const uint4 v1 = *(const uint4*)(act + 4);
        dot4(az, a_z0, v0); dot4(ar, a_r0, v0); dot4(a3, a_h0, v0);
        dot4(az, a_z1, v1); dot4(ar, a_r1, v1); dot4(a3, a_h1, v1);
        pz += 4 * COLS; pr += 4 * COLS; ph += 4 * COLS;
        if (c + 4 < NCH) {   // prefetch next A (chunks c+4,c+5); no OOB on last iter
            a_z0 = pz[0]; a_z1 = pz[COLS];
            a_r0 = pr[0]; a_r1 = pr[COLS];
            a_h0 = ph[0]; a_h1 = ph[COLS];
        }
        const uint4 v2 = *(const uint4*)(act + 8);
        const uint4 v3 = *(const uint4*)(act + 12);
        act += 16;
        dot4(az, b_z0, v2); dot4(ar, b_r0, v2); dot4(a3, b_h0, v2);
        dot4(az, b_z1, v3); dot4(ar, b_r1, v3); dot4(a3, b_h1, v3);
    }
}

// 256 WGs x 512 threads (8 waves/CU = 2/SIMD), one batch row per WG.
// K-split: GRU1 by 2 (kh = tid&1), GRU2 by 4 (kq = tid&3); shfl_xor reduce.
// One barrier per timestep.
__global__ __launch_bounds__(512, 2)
void gru_fused(const float* __restrict__ x,
               const float* __restrict__ b1, const float* __restrict__ b2,
               const float* __restrict__ w3, const float* __restrict__ b3,
               const float* __restrict__ w4, const float* __restrict__ b4,
               const float* __restrict__ w5, const float* __restrict__ b5,
               const unsigned int* __restrict__ wp,
               float* __restrict__ out)
{
    // fp16 activation pair buffers (uint = one half2), double-buffered.
    // act1: pairs [0..31] = x(t) (64 feats), pairs [32..159] = h1 (256 units)
    // act2: pairs [0..63] = h2 (128 units)
    __shared__ __align__(16) unsigned int act1[2][160];
    __shared__ __align__(16) unsigned int act2[2][64];
    __shared__ float h2fin[NU2];
    __shared__ float d3[64];
    __shared__ float d4[32];

    const int tid = threadIdx.x;
    const int row = blockIdx.x;
    const int j   = tid >> 1;       // GRU1 column (0..255)
    const int kh  = tid & 1;        // GRU1 K-half
    const int c2  = tid >> 2;       // GRU2 column (0..127)
    const int kq  = tid & 3;        // GRU2 K-quarter

    for (int i = tid; i < 2 * 160; i += 512) (&act1[0][0])[i] = 0u;
    for (int i = tid; i < 2 * 64;  i += 512) (&act2[0][0])[i] = 0u;

    // GRU1 biases (z,r folded; h kept split for reset_after), counted once via kh mask
    const float bm1  = (kh == 0) ? 1.0f : 0.0f;
    const float bz1  = (b1[j] + b1[768 + j]) * bm1;
    const float br1  = (b1[256 + j] + b1[1024 + j]) * bm1;
    const float bxh1 = b1[512 + j] * bm1;
    const float brh1 = b1[1280 + j] * bm1;
    // GRU2 biases, counted once via kq mask
    const float bm2  = (kq == 0) ? 1.0f : 0.0f;
    const float bz2  = (b2[c2] + b2[384 + c2]) * bm2;
    const float br2  = (b2[128 + c2] + b2[512 + c2]) * bm2;
    const float bxh2 = b2[256 + c2] * bm2;
    const float brh2 = b2[640 + c2] * bm2;

    const uint4* wp4 = (const uint4*)wp;
    const uint4* g1z = wp4 + G1Z_U4 + (kh * 20) * 256 + j;
    const uint4* g1r = wp4 + G1R_U4 + (kh * 20) * 256 + j;
    const uint4* g1h = wp4 + G1H_U4 + (kh * 20) * 256 + j;
    const uint4* g2z = wp4 + G2Z_U4 + (kq * 12) * 128 + c2;
    const uint4* g2r = wp4 + G2R_U4 + (kq * 12) * 128 + c2;
    const uint4* g2h = wp4 + G2H_U4 + (kq * 12) * 128 + c2;

    __syncthreads();   // zeros visible before x(0) pack overwrites x-part

    if (tid < FEAT) {
        float x0 = x[(size_t)row * TSEQ * FEAT + tid];
        float xb = __shfl_xor(x0, 1);
        if ((tid & 1) == 0) act1[0][tid >> 1] = pack2(x0, xb);
    }
    __syncthreads();

    float hp1 = 0.0f;   // h1 previous state, col j (redundant on the lane pair)
    float hp2 = 0.0f;   // h2 previous state, col c2 (redundant on the lane quad)

    for (int t = 0; t < TSEQ; ++t) {
        const int cur = t & 1, nb = cur ^ 1;

        // prefetch next x into registers (packed to LDS before the barrier)
        float xpre = 0.0f;
        if (t + 1 < TSEQ && tid < FEAT)
            xpre = x[(size_t)row * TSEQ * FEAT + (t + 1) * FEAT + tid];

        // ---------------- GRU1: reads act1[cur]; writes act1[nb] ----------------
        float az = bz1, ar = br1, aA = bxh1, aB = brh1;
        seg3<256, 4 >(g1z, g1r, g1h, &act1[cur][kh * 16], az, ar, aA);
        seg3<256, 16>(g1z + 4 * 256, g1r + 4 * 256, g1h + 4 * 256,
                      &act1[cur][32 + kh * 64], az, ar, aB);
        az += __shfl_xor(az, 1);
        ar += __shfl_xor(ar, 1);
        aA += __shfl_xor(aA, 1);
        aB += __shfl_xor(aB, 1);
        {
            const float z  = sigmoid_f(az);
            const float rg = sigmoid_f(ar);
            const float hh = tanh_f(aA + rg * aB);
            const float hn = z * hp1 + (1.0f - z) * hh;
            hp1 = hn;
            const float hnb = __shfl_xor(hn, 2);   // partner column (2m+1) on lane 4m
            if ((tid & 3) == 0) act1[nb][32 + (tid >> 2)] = pack2(hn, hnb);
        }
        if (t + 1 < TSEQ && tid < FEAT) {
            float xb = __shfl_xor(xpre, 1);
            if ((tid & 1) == 0) act1[nb][tid >> 1] = pack2(xpre, xb);
        }
        __syncthreads();   // THE one barrier: act1[nb] (h1(t) + x(t+1)) visible

        // ---------------- GRU2: reads act1[nb] h-part, act2[cur]; writes act2[nb] ----------------
        float az2 = bz2, ar2 = br2, aA2 = bxh2, aB2 = brh2;
        seg3<128, 8>(g2z, g2r, g2h, &act1[nb][32 + kq * 32], az2, ar2, aA2);
        seg3<128, 4>(g2z + 8 * 128, g2r + 8 * 128, g2h + 8 * 128,
                     &act2[cur][kq * 16], az2, ar2, aB2);
        az2 += __shfl_xor(az2, 1); az2 += __shfl_xor(az2, 2);
        ar2 += __shfl_xor(ar2, 1); ar2 += __shfl_xor(ar2, 2);
        aA2 += __shfl_xor(aA2, 1); aA2 += __shfl_xor(aA2, 2);
        aB2 += __shfl_xor(aB2, 1); aB2 += __shfl_xor(aB2, 2);
        {
            const float z2v = sigmoid_f(az2);
            const float rg2 = sigmoid_f(ar2);
            const float hh2 = tanh_f(aA2 + rg2 * aB2);
            const float hn2 = z2v * hp2 + (1.0f - z2v) * hh2;
            hp2 = hn2;
            const float hnb2 = __shfl_xor(hn2, 4); // partner column (2m+1) on lane 8m
            if ((tid & 7) == 0) act2[nb][tid >> 3] = pack2(hn2, hnb2);
        }
        // no second barrier: next step's barrier covers act2[nb] visibility;
        // all WAR hazards are buffer-separated (same discipline as proven kernel)
    }

    if ((tid & 3) == 0) h2fin[c2] = hp2;   // final h2 state, fp32
    __syncthreads();

    // ---------------- dense head: h2 -> 64 -> 32 -> 24 ----------------
    if (tid < 64) {
        float a = b3[tid];
        #pragma unroll 4
        for (int u = 0; u < NU2; ++u) a += h2fin[u] * w3[u * 64 + tid];
        d3[tid] = a;
    }
    __syncthreads();
    if (tid < 32) {
        float a = b4[tid];
        #pragma unroll 4
        for (int u = 0; u < 64; ++u) a += d3[u] * w4[u * 32 + tid];
        d4[tid] = a;
    }
    __syncthreads();
    if (tid < 24) {
        float a = b5[tid];
        #pragma unroll 4
        for (int u = 0; u < 32; ++u) a += d4[u] * w5[u * 24 + tid];
        out[(size_t)row * 24 + tid] = a;
    }
}

extern "C" void kernel_launch(void* const* d_in, const int* in_sizes, int n_in,
                              void* d_out, int out_size, void* d_ws, size_t ws_size,
                              hipStream_t stream) {
    (void)in_sizes; (void)n_in; (void)ws_size; (void)out_size;
    const float* x  = (const float*)d_in[0];
    const float* k1 = (const float*)d_in[1];
    const float* r1 = (const float*)d_in[2];
    const float* b1 = (const float*)d_in[3];
    const float* k2 = (const float*)d_in[4];
    const float* r2 = (const float*)d_in[5];
    const float* b2 = (const float*)d_in[6];
    const float* w3 = (const float*)d_in[7];
    const float* b3 = (const float*)d_in[8];
    const float* w4 = (const float*)d_in[9];
    const float* b4 = (const float*)d_in[10];
    const float* w5 = (const float*)d_in[11];
    const float* b5 = (const float*)d_in[12];
    float* out = (float*)d_out;

    hipLaunchKernelGGL(pack_weights, dim3((TOTAL_H2 + 255) / 256), dim3(256), 0, stream,
                       k1, r1, k2, r2, (__half2*)d_ws);
    hipLaunchKernelGGL(gru_fused, dim3(BATCH), dim3(512), 0, stream,
                       x, b1, b2, w3, b3, w4, b4, w5, b5,
                       (const unsigned int*)d_ws, out);
}